// Round 2
// baseline (355.449 us; speedup 1.0000x reference)
//
#include <hip/hip_runtime.h>
#include <math.h>

namespace {

constexpr int H_DIM = 4096;   // hidden size
constexpr int NE    = 8;      // num experts
constexpr int TPB   = 16;     // tokens per block
constexpr int NW    = 8;      // waves per block (512 threads)
constexpr int HPW   = 512;    // H-slice per wave (8 waves * 512 = 4096)

// Block = 512 threads = 8 waves. Wave w owns h in [w*512, (w+1)*512).
// Lane l owns h positions w*512 + j*256 + l*4 (j=0..1) as float4 -> perfectly
// coalesced 1 KiB/wave/load. W slice in registers: 8 experts x 2 float4 =
// 64 VGPRs, loaded once (L2-hit), reused for all 16 tokens of the block.
// ~110 VGPR total -> 4 waves/SIMD under __launch_bounds__(512,4).
__global__ __launch_bounds__(512, 4)
void router_kernel(const float* __restrict__ x, const float* __restrict__ W,
                   float* __restrict__ out, int ntok) {
    const int tid  = threadIdx.x;
    const int wave = tid >> 6;
    const int lane = tid & 63;

    // ---- W preload into registers ----
    float4 wr[NE][2];
    #pragma unroll
    for (int e = 0; e < NE; ++e) {
        const float4* Wrow = (const float4*)(W + e * H_DIM + wave * HPW);
        #pragma unroll
        for (int j = 0; j < 2; ++j) wr[e][j] = Wrow[j * 64 + lane];
    }

    __shared__ float part[TPB][NW][NE];  // [token][wave][expert] partials, 4 KiB

    int tok0 = (int)blockIdx.x * TPB;
    if (tok0 + TPB > ntok) tok0 = ntok - TPB;  // clamp tail (benign idempotent overlap)

    const float* xbase = x + (size_t)tok0 * H_DIM + wave * HPW;

    // software pipeline: prefetch next token's x while computing current
    float4 xv[2], xn[2];
    {
        const float4* xr = (const float4*)xbase;
        #pragma unroll
        for (int j = 0; j < 2; ++j) xv[j] = xr[j * 64 + lane];
    }

    for (int t = 0; t < TPB; ++t) {
        if (t + 1 < TPB) {
            const float4* xrn = (const float4*)(xbase + (size_t)(t + 1) * H_DIM);
            #pragma unroll
            for (int j = 0; j < 2; ++j) xn[j] = xrn[j * 64 + lane];
        }

        // ---- 8 partial dot products (per-lane, 64 FMAs) ----
        float v[NE];
        #pragma unroll
        for (int e = 0; e < NE; ++e) {
            float a = 0.0f;
            #pragma unroll
            for (int j = 0; j < 2; ++j) {
                a += xv[j].x * wr[e][j].x;
                a += xv[j].y * wr[e][j].y;
                a += xv[j].z * wr[e][j].z;
                a += xv[j].w * wr[e][j].w;
            }
            v[e] = a;
        }

        // ---- folded butterfly reduction: 8 accs over 64 lanes ----
        // After 3 fold steps, v[0]@lane holds the 8-lane-group sum of expert
        // e(lane) = 4*bit0 + 2*bit1 + 1*bit2; then 3 xor steps sum the groups.
        const bool b0 = (lane & 1) != 0;
        #pragma unroll
        for (int i = 0; i < 4; ++i) {
            float a = b0 ? v[i + 4] : v[i];
            float b = b0 ? v[i]     : v[i + 4];
            v[i] = a + __shfl_xor(b, 1, 64);
        }
        const bool b1 = (lane & 2) != 0;
        #pragma unroll
        for (int i = 0; i < 2; ++i) {
            float a = b1 ? v[i + 2] : v[i];
            float b = b1 ? v[i]     : v[i + 2];
            v[i] = a + __shfl_xor(b, 2, 64);
        }
        const bool b2 = (lane & 4) != 0;
        {
            float a = b2 ? v[1] : v[0];
            float b = b2 ? v[0] : v[1];
            float s = a + __shfl_xor(b, 4, 64);
            s += __shfl_xor(s, 8, 64);
            s += __shfl_xor(s, 16, 64);
            s += __shfl_xor(s, 32, 64);
            if (lane < 8) {
                const int e = ((lane & 1) << 2) | (lane & 2) | ((lane >> 2) & 1);
                part[t][wave][e] = s;  // distinct [t][wave] slots -> no race
            }
        }

        #pragma unroll
        for (int j = 0; j < 2; ++j) xv[j] = xn[j];
    }

    __syncthreads();

    // ---- epilogue: one thread per token ----
    if (tid < TPB) {
        const int tok = tok0 + tid;
        float lg[NE];
        #pragma unroll
        for (int e = 0; e < NE; ++e) {
            float a = 0.0f;
            #pragma unroll
            for (int w = 0; w < NW; ++w) a += part[tid][w][e];
            lg[e] = a;
        }

        float* out_w = out;                      // routing_weights [N,2]
        float* out_s = out + (size_t)ntok * 2;   // selected_experts [N,2] (as floats)
        float* out_l = out + (size_t)ntok * 4;   // router_logits [N,8]

        float4* lp = (float4*)(out_l + (size_t)tok * 8);
        lp[0] = make_float4(lg[0], lg[1], lg[2], lg[3]);
        lp[1] = make_float4(lg[4], lg[5], lg[6], lg[7]);

        // top-2 over logits (== top-2 over softmax probs; ties -> lower index
        // first, matching jax.lax.top_k stability)
        int e0 = 0; float m0 = lg[0];
        #pragma unroll
        for (int e = 1; e < NE; ++e) { if (lg[e] > m0) { m0 = lg[e]; e0 = e; } }
        int e1 = -1; float m1 = -INFINITY;
        #pragma unroll
        for (int e = 0; e < NE; ++e) { if (e != e0 && lg[e] > m1) { m1 = lg[e]; e1 = e; } }

        // softmax over the two gathered logits (m0 >= m1)
        const float d = expf(m1 - m0);
        const float s = 1.0f / (1.0f + d);
        out_w[(size_t)tok * 2]     = s;
        out_w[(size_t)tok * 2 + 1] = d * s;
        out_s[(size_t)tok * 2]     = (float)e0;
        out_s[(size_t)tok * 2 + 1] = (float)e1;
    }
}

} // namespace

extern "C" void kernel_launch(void* const* d_in, const int* in_sizes, int n_in,
                              void* d_out, int out_size, void* d_ws, size_t ws_size,
                              hipStream_t stream) {
    const float* x = (const float*)d_in[0];  // hidden_states [4,4096,4096] f32
    const float* W = (const float*)d_in[1];  // router weight [8,4096] f32
    float* outp = (float*)d_out;             // 12*N floats

    const int ntok = in_sizes[0] / H_DIM;    // 16384
    const int nblk = (ntok + TPB - 1) / TPB; // 1024 blocks x 512 threads

    router_kernel<<<nblk, 512, 0, stream>>>(x, W, outp, ntok);
}

// Round 4
// 342.723 us; speedup vs baseline: 1.0371x; 1.0371x over previous
//
#include <hip/hip_runtime.h>
#include <math.h>

namespace {

constexpr int H_DIM = 4096;   // hidden size
constexpr int NE    = 8;      // num experts
constexpr int TPB   = 16;     // tokens per block
constexpr int NW    = 16;     // waves per block (1024 threads)
constexpr int HPW   = 256;    // H-slice per wave (16 waves * 256 = 4096)
constexpr int PF    = 4;      // prefetch depth (tokens in flight per wave)

// native clang vector type: __builtin_nontemporal_load requires it
typedef float f32x4 __attribute__((ext_vector_type(4)));

// Block = 1024 threads = 16 waves. Wave w owns h in [w*256, (w+1)*256).
// Lane l owns the float4 at w*256 + l*4 -> one perfectly coalesced 1 KiB
// load per token per wave. W slice in registers: 8 experts x 1 float4 =
// 32 VGPRs, loaded once (L2-hit), reused for all 16 tokens.
// Ring of 4 token-slices in flight -> 4 KB outstanding/wave, 64 KB/CU.
__global__ __launch_bounds__(1024, 4)
void router_kernel(const float* __restrict__ x, const float* __restrict__ W,
                   float* __restrict__ out, int ntok) {
    const int tid  = threadIdx.x;
    const int wave = tid >> 6;
    const int lane = tid & 63;

    // ---- W preload into registers ----
    f32x4 wr[NE];
    #pragma unroll
    for (int e = 0; e < NE; ++e) {
        const f32x4* Wrow = (const f32x4*)(W + e * H_DIM + wave * HPW);
        wr[e] = Wrow[lane];
    }

    __shared__ float part[TPB][NW][NE];  // [token][wave][expert] partials, 8 KiB

    int tok0 = (int)blockIdx.x * TPB;
    if (tok0 + TPB > ntok) tok0 = ntok - TPB;  // clamp tail (benign idempotent overlap)

    const float* xbase = x + (size_t)tok0 * H_DIM + wave * HPW;

    // ---- ring-buffer prefetch, depth 4, non-temporal (x is streamed once) ----
    f32x4 xb[PF];
    #pragma unroll
    for (int p = 0; p < PF; ++p)
        xb[p] = __builtin_nontemporal_load((const f32x4*)(xbase + (size_t)p * H_DIM) + lane);

    #pragma unroll
    for (int t = 0; t < TPB; ++t) {
        const f32x4 xv = xb[t & (PF - 1)];
        if (t + PF < TPB)
            xb[t & (PF - 1)] = __builtin_nontemporal_load(
                (const f32x4*)(xbase + (size_t)(t + PF) * H_DIM) + lane);

        // ---- 8 partial dot products (per-lane, 32 FMAs) ----
        float v[NE];
        #pragma unroll
        for (int e = 0; e < NE; ++e) {
            v[e] = xv.x * wr[e].x + xv.y * wr[e].y + xv.z * wr[e].z + xv.w * wr[e].w;
        }

        // ---- folded butterfly reduction: 8 accs over 64 lanes ----
        // After 3 fold steps, v[0]@lane holds the 8-lane-group sum of expert
        // e(lane) = 4*bit0 + 2*bit1 + 1*bit2; then 3 xor steps sum the groups.
        const bool b0 = (lane & 1) != 0;
        #pragma unroll
        for (int i = 0; i < 4; ++i) {
            float a = b0 ? v[i + 4] : v[i];
            float b = b0 ? v[i]     : v[i + 4];
            v[i] = a + __shfl_xor(b, 1, 64);
        }
        const bool b1 = (lane & 2) != 0;
        #pragma unroll
        for (int i = 0; i < 2; ++i) {
            float a = b1 ? v[i + 2] : v[i];
            float b = b1 ? v[i]     : v[i + 2];
            v[i] = a + __shfl_xor(b, 2, 64);
        }
        const bool b2 = (lane & 4) != 0;
        {
            float a = b2 ? v[1] : v[0];
            float b = b2 ? v[0] : v[1];
            float s = a + __shfl_xor(b, 4, 64);
            s += __shfl_xor(s, 8, 64);
            s += __shfl_xor(s, 16, 64);
            s += __shfl_xor(s, 32, 64);
            if (lane < 8) {
                const int e = ((lane & 1) << 2) | (lane & 2) | ((lane >> 2) & 1);
                part[t][wave][e] = s;  // distinct [t][wave] slots -> no race
            }
        }
    }

    __syncthreads();

    // ---- epilogue: one thread per token ----
    if (tid < TPB) {
        const int tok = tok0 + tid;
        float lg[NE];
        #pragma unroll
        for (int e = 0; e < NE; ++e) {
            float a = 0.0f;
            #pragma unroll
            for (int w = 0; w < NW; ++w) a += part[tid][w][e];
            lg[e] = a;
        }

        float* out_w = out;                      // routing_weights [N,2]
        float* out_s = out + (size_t)ntok * 2;   // selected_experts [N,2] (as floats)
        float* out_l = out + (size_t)ntok * 4;   // router_logits [N,8]

        float4* lp = (float4*)(out_l + (size_t)tok * 8);
        lp[0] = make_float4(lg[0], lg[1], lg[2], lg[3]);
        lp[1] = make_float4(lg[4], lg[5], lg[6], lg[7]);

        // top-2 over logits (== top-2 over softmax probs; ties -> lower index
        // first, matching jax.lax.top_k stability)
        int e0 = 0; float m0 = lg[0];
        #pragma unroll
        for (int e = 1; e < NE; ++e) { if (lg[e] > m0) { m0 = lg[e]; e0 = e; } }
        int e1 = -1; float m1 = -INFINITY;
        #pragma unroll
        for (int e = 0; e < NE; ++e) { if (e != e0 && lg[e] > m1) { m1 = lg[e]; e1 = e; } }

        // softmax over the two gathered logits (m0 >= m1)
        const float d = expf(m1 - m0);
        const float s = 1.0f / (1.0f + d);
        out_w[(size_t)tok * 2]     = s;
        out_w[(size_t)tok * 2 + 1] = d * s;
        out_s[(size_t)tok * 2]     = (float)e0;
        out_s[(size_t)tok * 2 + 1] = (float)e1;
    }
}

} // namespace

extern "C" void kernel_launch(void* const* d_in, const int* in_sizes, int n_in,
                              void* d_out, int out_size, void* d_ws, size_t ws_size,
                              hipStream_t stream) {
    const float* x = (const float*)d_in[0];  // hidden_states [4,4096,4096] f32
    const float* W = (const float*)d_in[1];  // router weight [8,4096] f32
    float* outp = (float*)d_out;             // 12*N floats

    const int ntok = in_sizes[0] / H_DIM;    // 16384
    const int nblk = (ntok + TPB - 1) / TPB; // 1024 blocks x 1024 threads

    router_kernel<<<nblk, 1024, 0, stream>>>(x, W, outp, ntok);
}